// Round 7
// baseline (251.550 us; speedup 1.0000x reference)
//
#include <hip/hip_runtime.h>
#include <cstdint>
#include <cstddef>

#define BB 8
#define SS 8192
#define DD 64
#define HH 8
#define NB 128
#define NCHUNK 128   /* S / 64 */
#define CHUNKS 1024  /* H * NB */

typedef __attribute__((ext_vector_type(8))) short bf16x8;
typedef __attribute__((ext_vector_type(4))) float f32x4;

__device__ __forceinline__ unsigned short f2b(float x) {
  union { float f; unsigned int u; } c; c.f = x;
  unsigned int r = c.u + 0x7fffu + ((c.u >> 16) & 1u);
  return (unsigned short)(r >> 16);
}
__device__ __forceinline__ float b2f(unsigned short h) {
  union { unsigned int u; float f; } c; c.u = ((unsigned int)h) << 16;
  return c.f;
}

// ---------------------------------------------------------------------------
// Kernel 0: prep — qhat = normalize(qk) in bf16, snorm = sqrt(ssq+eps) f32,
// vb = v in bf16. Fully coalesced. 8 lanes per row.
// ---------------------------------------------------------------------------
__global__ __launch_bounds__(256) void prep_kernel(const float* __restrict__ qk,
                                                   const float* __restrict__ v,
                                                   unsigned short* __restrict__ qhat,
                                                   unsigned short* __restrict__ vb,
                                                   float* __restrict__ snorm) {
  const int idx = blockIdx.x * 256 + threadIdx.x;
  const int row = idx >> 3, seg = idx & 7;
  const size_t base = (size_t)row * DD + seg * 8;

  float4 a0 = ((const float4*)(qk + base))[0];
  float4 a1 = ((const float4*)(qk + base))[1];
  float vals[8] = {a0.x, a0.y, a0.z, a0.w, a1.x, a1.y, a1.z, a1.w};
  float ssq = 0.f;
#pragma unroll
  for (int k = 0; k < 8; ++k) ssq += vals[k] * vals[k];
  ssq += __shfl_xor(ssq, 1);
  ssq += __shfl_xor(ssq, 2);
  ssq += __shfl_xor(ssq, 4);
  const float r = rsqrtf(ssq + 1e-6f);
  const float sn = (ssq + 1e-6f) * r;  // sqrt(ssq + eps)
  uint4 qo;
  unsigned int* qp = (unsigned int*)&qo;
#pragma unroll
  for (int k = 0; k < 4; ++k)
    qp[k] = (unsigned int)f2b(vals[2 * k] * r) | ((unsigned int)f2b(vals[2 * k + 1] * r) << 16);
  *(uint4*)(qhat + base) = qo;
  if (seg == 0) snorm[row] = sn;

  float4 v0 = ((const float4*)(v + base))[0];
  float4 v1 = ((const float4*)(v + base))[1];
  float vv[8] = {v0.x, v0.y, v0.z, v0.w, v1.x, v1.y, v1.z, v1.w};
  uint4 vo;
  unsigned int* vp = (unsigned int*)&vo;
#pragma unroll
  for (int k = 0; k < 4; ++k)
    vp[k] = (unsigned int)f2b(vv[2 * k]) | ((unsigned int)f2b(vv[2 * k + 1]) << 16);
  *(uint4*)(vb + base) = vo;
}

// ---------------------------------------------------------------------------
// Kernel 1: LSH hash. T=8 rows x C=2 cols per thread. q rows read from
// global (L1-resident broadcast, off the LDS pipe); rot staged per h in LDS
// and read as ds_read_b64. FMA chains bitwise-identical to prior passing
// versions (serial f=0..63 fmac per output, same argmax eval order/tie
// rule). Grid (NCHUNK, BB), 256 thr.
// ---------------------------------------------------------------------------
__global__ __launch_bounds__(256) void hash_kernel(const float* __restrict__ qk,
                                                   const float* __restrict__ rot,
                                                   unsigned char* __restrict__ bucket) {
  __shared__ __align__(16) float rs[64][68];
  const int tid = threadIdx.x;
  const int b = blockIdx.y, tile = blockIdx.x;
  const int lane = tid & 63, w = tid >> 6;
  const int colg = lane & 31;          // 32 column groups
  const int rowg = w * 2 + (lane >> 5);  // 8 row groups
  const int r0 = rowg * 8;             // rows r0..r0+7
  const int c0 = colg * 2;             // cols c0, c0+1

  const float* qbase = qk + ((size_t)b * SS + (size_t)tile * 64 + r0) * DD;

  for (int h = 0; h < HH; ++h) {
    __syncthreads();  // previous phase's rs readers done
    // stage rs[f][i] = rot[f][h*64+i]: dwordx4 global -> b128 LDS
#pragma unroll
    for (int rep = 0; rep < 4; ++rep) {
      const int flat = rep * 1024 + tid * 4;
      const int f = flat >> 6, i = flat & 63;
      const float4 vv = *(const float4*)(rot + (size_t)f * (HH * 64) + h * 64 + i);
      *(float4*)&rs[f][i] = vv;
    }
    __syncthreads();

    float acc[8][2];
#pragma unroll
    for (int r = 0; r < 8; ++r) { acc[r][0] = 0.f; acc[r][1] = 0.f; }

#pragma unroll 4
    for (int f4 = 0; f4 < 16; ++f4) {
      float4 qv[8];
#pragma unroll
      for (int r = 0; r < 8; ++r)
        qv[r] = *(const float4*)(qbase + r * DD + f4 * 4);
#pragma unroll
      for (int ff = 0; ff < 4; ++ff) {
        const float2 rv = *(const float2*)&rs[f4 * 4 + ff][c0];
        const float rx = rv.x, ry = rv.y;
#pragma unroll
        for (int r = 0; r < 8; ++r) {
          const float qq = ((const float*)&qv[r])[ff];
          acc[r][0] += qq * rx;
          acc[r][1] += qq * ry;
        }
      }
    }

    // per-row argmax over [rot, -rot]; reduce over the 32 colg lanes.
    // Tie rule: greater value, then lower index (pos indices < neg indices).
    unsigned long long packed = 0ull;
#pragma unroll
    for (int r = 0; r < 8; ++r) {
      float bv = -3.4e38f;
      int bi = 0;
#pragma unroll
      for (int c = 0; c < 2; ++c) {
        const int i = c0 + c;
        const float vp = acc[r][c];
        if (vp > bv || (vp == bv && i < bi)) { bv = vp; bi = i; }
        const float vn = -vp;
        if (vn > bv || (vn == bv && (i + 64) < bi)) { bv = vn; bi = i + 64; }
      }
#pragma unroll
      for (int off = 1; off < 32; off <<= 1) {
        const float ov = __shfl_xor(bv, off);
        const int oi = __shfl_xor(bi, off);
        if (ov > bv || (ov == bv && oi < bi)) { bv = ov; bi = oi; }
      }
      packed |= ((unsigned long long)(unsigned int)(bi & 0xff)) << (8 * r);
    }
    if (colg == 0)
      *(unsigned long long*)&bucket[((size_t)(b * HH + h)) * SS + (size_t)tile * 64 + r0] = packed;
  }
}

// ---------------------------------------------------------------------------
// Kernel 2: stable counting sort per (b,h), 1024 threads.
// ---------------------------------------------------------------------------
__global__ __launch_bounds__(1024) void sort_kernel(const unsigned char* __restrict__ bucket,
                                                    int* __restrict__ sticker) {
  __shared__ unsigned char lb[SS];
  __shared__ unsigned int hist[NB * NCHUNK];
  __shared__ unsigned int ssum[1024];
  const int tid = threadIdx.x;
  const int bh = blockIdx.x;

  if (tid < 512)
    ((uint4*)lb)[tid] = ((const uint4*)(bucket + (size_t)bh * SS))[tid];
#pragma unroll
  for (int k = 0; k < (NB * NCHUNK) / 1024; ++k) hist[tid + k * 1024] = 0u;
  __syncthreads();

#pragma unroll
  for (int rep = 0; rep < SS / 1024; ++rep) {
    const int t = rep * 1024 + tid;
    atomicAdd(&hist[(int)lb[t] * NCHUNK + (t >> 6)], 1u);
  }
  __syncthreads();

  unsigned int segsum = 0u;
  const int base = tid * 16;
#pragma unroll
  for (int e = 0; e < 16; ++e) segsum += hist[base + e];
  ssum[tid] = segsum;
  __syncthreads();
  for (int off = 1; off < 1024; off <<= 1) {
    const unsigned int vv = (tid >= off) ? ssum[tid - off] : 0u;
    __syncthreads();
    ssum[tid] += vv;
    __syncthreads();
  }
  unsigned int run = ssum[tid] - segsum;
#pragma unroll
  for (int e = 0; e < 16; ++e) {
    const unsigned int tv = hist[base + e];
    hist[base + e] = run;
    run += tv;
  }
  __syncthreads();

  const int wid = tid >> 6, lane = tid & 63;
#pragma unroll
  for (int rep = 0; rep < NCHUNK / 16; ++rep) {
    const int c = rep * 16 + wid;
    const int t = c * 64 + lane;
    const int bk = lb[t];
    unsigned long long mm = ~0ull;
#pragma unroll
    for (int bit = 0; bit < 7; ++bit) {
      const unsigned long long bal = __ballot((bk >> bit) & 1);
      mm &= ((bk >> bit) & 1) ? bal : ~bal;
    }
    const int rank = __popcll(mm & ((1ull << lane) - 1ull));
    const int pos = (int)hist[bk * NCHUNK + c] + rank;
    sticker[(size_t)bh * SS + pos] = t;
  }
}

// ---------------------------------------------------------------------------
// Kernel 3: fused attention from precomputed bf16 qhat/vb + f32 snorm.
// Grid (NB, 4, HH) per b-half. Writes normalized o_h (bf16, layout b,t,h,d)
// and lse_h (f32, layout b,t,h), scattered by original t.
// ---------------------------------------------------------------------------
__global__ __launch_bounds__(256) void attn_kernel(const unsigned short* __restrict__ qhat,
                                                   const unsigned short* __restrict__ vb,
                                                   const float* __restrict__ snorm,
                                                   const int* __restrict__ sticker,
                                                   unsigned short* __restrict__ so,
                                                   float* __restrict__ slogits,
                                                   const int b_base) {
  __shared__ __align__(16) unsigned short kbps[128 * 72];   // aliased: kb -> ps -> ob
  __shared__ __align__(16) unsigned short vt[64][136];
  __shared__ int st[128];
  __shared__ float sn_s[64];
  const int tid = threadIdx.x;
  const int bin = blockIdx.x, bl = blockIdx.y, h = blockIdx.z;
  const int b = b_base + bl;
  const int bh = b * HH + h;
  const int prev = (h * NB + bin + CHUNKS - 1) & (CHUNKS - 1);
  const int ph = prev >> 7, pbin = prev & 127;

  if (tid < 128) {
    const int j = tid;
    const int src = (j < 64) ? (bh * SS + bin * 64 + j)
                             : ((b * HH + ph) * SS + pbin * 64 + (j - 64));
    st[j] = sticker[src];
  }
  __syncthreads();

  {
    const int row = tid >> 1, half = tid & 1;
    const int trow = st[row];
    {
      const uint4* qsrc = (const uint4*)(qhat + ((size_t)b * SS + trow) * DD) + half * 4;
      uint4 q0 = qsrc[0], q1 = qsrc[1], q2 = qsrc[2], q3 = qsrc[3];
      unsigned short* kd = &kbps[row * 72 + half * 32];
      *(uint4*)&kd[0] = q0;
      *(uint4*)&kd[8] = q1;
      *(uint4*)&kd[16] = q2;
      *(uint4*)&kd[24] = q3;
    }
    {
      const uint4* vsrc = (const uint4*)(vb + ((size_t)b * SS + trow) * DD) + half * 4;
      uint4 w0 = vsrc[0], w1 = vsrc[1], w2 = vsrc[2], w3 = vsrc[3];
      unsigned int uu[16] = {w0.x, w0.y, w0.z, w0.w, w1.x, w1.y, w1.z, w1.w,
                             w2.x, w2.y, w2.z, w2.w, w3.x, w3.y, w3.z, w3.w};
#pragma unroll
      for (int m = 0; m < 16; ++m) {
        vt[half * 32 + 2 * m][row] = (unsigned short)(uu[m] & 0xffffu);
        vt[half * 32 + 2 * m + 1][row] = (unsigned short)(uu[m] >> 16);
      }
    }
  }
  if (tid < 64) sn_s[tid] = snorm[(size_t)b * SS + st[tid]];
  __syncthreads();

  const int lane = tid & 63, w = tid >> 6;
  const int r16 = lane & 15, g = lane >> 4;

  f32x4 acc[8];
#pragma unroll
  for (int n = 0; n < 8; ++n) acc[n] = (f32x4){0.f, 0.f, 0.f, 0.f};
  bf16x8 af0 = *(const bf16x8*)&kbps[(16 * w + r16) * 72 + g * 8];
  bf16x8 af1 = *(const bf16x8*)&kbps[(16 * w + r16) * 72 + 32 + g * 8];
#pragma unroll
  for (int n = 0; n < 8; ++n) {
    bf16x8 bf0 = *(const bf16x8*)&kbps[(16 * n + r16) * 72 + g * 8];
    bf16x8 bf1 = *(const bf16x8*)&kbps[(16 * n + r16) * 72 + 32 + g * 8];
    acc[n] = __builtin_amdgcn_mfma_f32_16x16x32_bf16(af0, bf0, acc[n], 0, 0, 0);
    acc[n] = __builtin_amdgcn_mfma_f32_16x16x32_bf16(af1, bf1, acc[n], 0, 0, 0);
  }

  int tkj[8];
#pragma unroll
  for (int n = 0; n < 8; ++n) tkj[n] = st[16 * n + r16];

  float lse4[4];
#pragma unroll
  for (int i = 0; i < 4; ++i) {
    const int q = 16 * w + 4 * g + i;
    const int tq = st[q];
    const float sq = sn_s[q] * 0.125f;
    float mm = -3.4e38f;
#pragma unroll
    for (int n = 0; n < 8; ++n) {
      float s = acc[n][i] * sq;
      s = (tkj[n] > tq) ? -1e38f : ((tkj[n] == tq) ? -50000.f : s);
      acc[n][i] = s;
      mm = fmaxf(mm, s);
    }
    mm = fmaxf(mm, __shfl_xor(mm, 1));
    mm = fmaxf(mm, __shfl_xor(mm, 2));
    mm = fmaxf(mm, __shfl_xor(mm, 4));
    mm = fmaxf(mm, __shfl_xor(mm, 8));
    float sum = 0.f;
#pragma unroll
    for (int n = 0; n < 8; ++n) sum += __expf(acc[n][i] - mm);
    sum += __shfl_xor(sum, 1);
    sum += __shfl_xor(sum, 2);
    sum += __shfl_xor(sum, 4);
    sum += __shfl_xor(sum, 8);
    const float lse = mm + logf(sum);
    lse4[i] = lse;
#pragma unroll
    for (int n = 0; n < 8; ++n) acc[n][i] = __expf(acc[n][i] - lse);
  }

  __syncthreads();  // kb reads done -> overwrite with ps

#pragma unroll
  for (int i = 0; i < 4; ++i) {
    const int q = 16 * w + 4 * g + i;
#pragma unroll
    for (int n = 0; n < 8; ++n)
      kbps[q * 136 + 16 * n + r16] = f2b(acc[n][i]);
  }
  if (r16 == 0) {
#pragma unroll
    for (int i = 0; i < 4; ++i) {
      const int q = 16 * w + 4 * g + i;
      slogits[((size_t)b * SS + st[q]) * HH + h] = lse4[i];
    }
  }
  __syncthreads();

  f32x4 o[4];
#pragma unroll
  for (int n = 0; n < 4; ++n) o[n] = (f32x4){0.f, 0.f, 0.f, 0.f};
#pragma unroll
  for (int kk = 0; kk < 4; ++kk) {
    bf16x8 pa = *(const bf16x8*)&kbps[(16 * w + r16) * 136 + kk * 32 + g * 8];
#pragma unroll
    for (int n = 0; n < 4; ++n) {
      bf16x8 vbf = *(const bf16x8*)&vt[16 * n + r16][kk * 32 + g * 8];
      o[n] = __builtin_amdgcn_mfma_f32_16x16x32_bf16(pa, vbf, o[n], 0, 0, 0);
    }
  }

  __syncthreads();  // ps reads done -> overwrite with ob
#pragma unroll
  for (int i = 0; i < 4; ++i) {
    const int q = 16 * w + 4 * g + i;
#pragma unroll
    for (int n = 0; n < 4; ++n)
      kbps[q * 72 + 16 * n + r16] = f2b(o[n][i]);
  }
  __syncthreads();

  {
    const int row = tid >> 2, q4 = tid & 3;
    uint4 x0 = *(const uint4*)&kbps[row * 72 + q4 * 16];
    uint4 x1 = *(const uint4*)&kbps[row * 72 + q4 * 16 + 8];
    unsigned short* dst = so + (((size_t)bl * SS + st[row]) * HH + h) * DD + q4 * 16;
    *(uint4*)&dst[0] = x0;
    *(uint4*)&dst[8] = x1;
  }
}

// ---------------------------------------------------------------------------
// Kernel 4: combine — out[b,t] = sum_h exp(l_h - LSE) * o_h[b,t,h].
// so layout (local b, t, h, d): contiguous per token.
// ---------------------------------------------------------------------------
__global__ __launch_bounds__(256) void gather_out_kernel(const unsigned short* __restrict__ so,
                                                         const float* __restrict__ slogits,
                                                         float* __restrict__ out,
                                                         const int b_base) {
  const int idx = blockIdx.x * 256 + threadIdx.x;  // (local bt, seg)
  const int seg = idx & 7;
  const int btl = idx >> 3;  // local row in [0, 4*SS)

  const float* lrow = slogits + ((size_t)b_base * SS + btl) * HH;
  float4 l0 = ((const float4*)lrow)[0];
  float4 l1 = ((const float4*)lrow)[1];
  float l[8] = {l0.x, l0.y, l0.z, l0.w, l1.x, l1.y, l1.z, l1.w};
  float m = -3.4e38f;
#pragma unroll
  for (int h = 0; h < HH; ++h) m = fmaxf(m, l[h]);
  float sum = 0.f;
#pragma unroll
  for (int h = 0; h < HH; ++h) sum += __expf(l[h] - m);
  const float lse = m + logf(sum);

  float acc[8];
#pragma unroll
  for (int k = 0; k < 8; ++k) acc[k] = 0.f;
#pragma unroll
  for (int h = 0; h < HH; ++h) {
    const float wgt = __expf(l[h] - lse);
    uint4 u = *(const uint4*)(so + ((size_t)btl * HH + h) * DD + seg * 8);
    const unsigned int uu[4] = {u.x, u.y, u.z, u.w};
#pragma unroll
    for (int k = 0; k < 4; ++k) {
      acc[2 * k] += wgt * b2f((unsigned short)(uu[k] & 0xffffu));
      acc[2 * k + 1] += wgt * b2f((unsigned short)(uu[k] >> 16));
    }
  }
  float* dst = out + ((size_t)b_base * SS + btl) * DD + seg * 8;
  float4 o0, o1;
  o0.x = acc[0]; o0.y = acc[1]; o0.z = acc[2]; o0.w = acc[3];
  o1.x = acc[4]; o1.y = acc[5]; o1.z = acc[6]; o1.w = acc[7];
  ((float4*)dst)[0] = o0;
  ((float4*)dst)[1] = o1;
}

// ---------------------------------------------------------------------------
extern "C" void kernel_launch(void* const* d_in, const int* in_sizes, int n_in,
                              void* d_out, int out_size, void* d_ws, size_t ws_size,
                              hipStream_t stream) {
  (void)in_sizes; (void)n_in; (void)out_size; (void)ws_size;
  const float* qk = (const float*)d_in[0];
  const float* v = (const float*)d_in[1];
  const float* rot = (const float*)d_in[2];
  float* out = (float*)d_out;

  char* ws = (char*)d_ws;
  int* sticker = (int*)ws;                                          // @0,   2 MB
  float* slogits = (float*)(ws + ((size_t)2 << 20));                // @2,   2 MB (b,t,h)
  float* snorm = (float*)(ws + ((size_t)4 << 20));                  // @4,   256 KB
  unsigned char* bucket = (unsigned char*)(ws + ((size_t)4 << 20) + ((size_t)256 << 10));  // 512 KB
  unsigned short* qhat = (unsigned short*)(ws + ((size_t)5 << 20)); // @5,   8 MB
  unsigned short* vb = (unsigned short*)(ws + ((size_t)13 << 20));  // @13,  8 MB
  unsigned short* so = (unsigned short*)(ws + ((size_t)21 << 20));  // @21, 32 MB (half-batch)

  prep_kernel<<<(BB * SS * 8) / 256, 256, 0, stream>>>(qk, v, qhat, vb, snorm);
  hash_kernel<<<dim3(NCHUNK, BB), 256, 0, stream>>>(qk, rot, bucket);
  sort_kernel<<<BB * HH, 1024, 0, stream>>>(bucket, sticker);

  for (int half = 0; half < 2; ++half) {
    const int b_base = half * (BB / 2);
    attn_kernel<<<dim3(NB, BB / 2, HH), 256, 0, stream>>>(qhat, vb, snorm, sticker, so, slogits, b_base);
    gather_out_kernel<<<(BB / 2 * SS * 8) / 256, 256, 0, stream>>>(so, slogits, out, b_base);
  }
}

// Round 8
// 185.858 us; speedup vs baseline: 1.3535x; 1.3535x over previous
//
#include <hip/hip_runtime.h>
#include <cstdint>
#include <cstddef>

#define BB 8
#define SS 8192
#define DD 64
#define HH 8
#define NB 128
#define NCHUNK 128   /* S / 64 */
#define CHUNKS 1024  /* H * NB */

typedef __attribute__((ext_vector_type(8))) short bf16x8;
typedef __attribute__((ext_vector_type(4))) float f32x4;

__device__ __forceinline__ unsigned short f2b(float x) {
  union { float f; unsigned int u; } c; c.f = x;
  unsigned int r = c.u + 0x7fffu + ((c.u >> 16) & 1u);
  return (unsigned short)(r >> 16);
}
__device__ __forceinline__ float b2f(unsigned short h) {
  union { unsigned int u; float f; } c; c.u = ((unsigned int)h) << 16;
  return c.f;
}

// ---------------------------------------------------------------------------
// Kernel 0: prep — qhat = normalize(qk) in bf16, snorm = sqrt(ssq+eps) f32,
// vb = v in bf16. Fully coalesced. 8 lanes per row.
// ---------------------------------------------------------------------------
__global__ __launch_bounds__(256) void prep_kernel(const float* __restrict__ qk,
                                                   const float* __restrict__ v,
                                                   unsigned short* __restrict__ qhat,
                                                   unsigned short* __restrict__ vb,
                                                   float* __restrict__ snorm) {
  const int idx = blockIdx.x * 256 + threadIdx.x;
  const int row = idx >> 3, seg = idx & 7;
  const size_t base = (size_t)row * DD + seg * 8;

  float4 a0 = ((const float4*)(qk + base))[0];
  float4 a1 = ((const float4*)(qk + base))[1];
  float vals[8] = {a0.x, a0.y, a0.z, a0.w, a1.x, a1.y, a1.z, a1.w};
  float ssq = 0.f;
#pragma unroll
  for (int k = 0; k < 8; ++k) ssq += vals[k] * vals[k];
  ssq += __shfl_xor(ssq, 1);
  ssq += __shfl_xor(ssq, 2);
  ssq += __shfl_xor(ssq, 4);
  const float r = rsqrtf(ssq + 1e-6f);
  const float sn = (ssq + 1e-6f) * r;  // sqrt(ssq + eps)
  uint4 qo;
  unsigned int* qp = (unsigned int*)&qo;
#pragma unroll
  for (int k = 0; k < 4; ++k)
    qp[k] = (unsigned int)f2b(vals[2 * k] * r) | ((unsigned int)f2b(vals[2 * k + 1] * r) << 16);
  *(uint4*)(qhat + base) = qo;
  if (seg == 0) snorm[row] = sn;

  float4 v0 = ((const float4*)(v + base))[0];
  float4 v1 = ((const float4*)(v + base))[1];
  float vv[8] = {v0.x, v0.y, v0.z, v0.w, v1.x, v1.y, v1.z, v1.w};
  uint4 vo;
  unsigned int* vp = (unsigned int*)&vo;
#pragma unroll
  for (int k = 0; k < 4; ++k)
    vp[k] = (unsigned int)f2b(vv[2 * k]) | ((unsigned int)f2b(vv[2 * k + 1]) << 16);
  *(uint4*)(vb + base) = vo;
}

// ---------------------------------------------------------------------------
// Kernel 1: LSH hash. Thread tile 8 rows x 8 cols (1 LDS byte per FMA).
// Block: 128 q rows x 128 cols (one h-pair per phase, 4 phases).
// Both operands from LDS (qsT transposed, rs per h-pair, coalesced since an
// h-pair's rot columns are contiguous). FMA chains bitwise-identical to the
// passing versions (serial f=0..63 fmac per output, same argmax tie rule).
// Grid (SS/128, BB), 256 thr.
// ---------------------------------------------------------------------------
__global__ __launch_bounds__(256) void hash_kernel(const float* __restrict__ qk,
                                                   const float* __restrict__ rot,
                                                   unsigned char* __restrict__ bucket) {
  __shared__ __align__(16) float qsT[64][132];   // [f][row], 128 rows + pad
  __shared__ __align__(16) float rs[64][136];    // [f][col-pair], 128 cols + pad
  const int tid = threadIdx.x;
  const int b = blockIdx.y, tile = blockIdx.x;

  // stage qsT (transposed): thread loads 32 consecutive f of one row
  {
    const int row = tid >> 1, part = tid & 1;
    const float4* src = (const float4*)(qk + ((size_t)b * SS + (size_t)tile * 128 + row) * DD + part * 32);
    float vals[32];
#pragma unroll
    for (int k = 0; k < 8; ++k) {
      float4 f = src[k];
      vals[k * 4 + 0] = f.x; vals[k * 4 + 1] = f.y; vals[k * 4 + 2] = f.z; vals[k * 4 + 3] = f.w;
    }
#pragma unroll
    for (int k = 0; k < 32; ++k) qsT[part * 32 + k][row] = vals[k];
  }

  const int colg = tid & 15, rowg = tid >> 4;
  const int r0 = rowg * 8;             // rows r0..r0+7 (of 128)
  const int c0 = colg * 8;             // cols c0..c0+7 (of 128 = 2 h)
  const int hloc = colg >> 3;          // which h of the pair
  const int i0 = c0 & 63;              // rotation index base within h

  for (int hp = 0; hp < 4; ++hp) {
    __syncthreads();  // prior rs readers done (also covers qsT staging, iter 0)
    // stage rs[f][j] = rot[f][hp*128 + j] (contiguous cols -> coalesced)
#pragma unroll
    for (int rep = 0; rep < 8; ++rep) {
      const int idx4 = rep * 256 + tid;
      const int f = idx4 >> 5, j4 = (idx4 & 31) << 2;
      const float4 vv = *(const float4*)(rot + (size_t)f * (HH * 64) + hp * 128 + j4);
      *(float4*)&rs[f][j4] = vv;
    }
    __syncthreads();

    float acc[8][8];
#pragma unroll
    for (int r = 0; r < 8; ++r)
#pragma unroll
      for (int c = 0; c < 8; ++c) acc[r][c] = 0.f;

#pragma unroll 4
    for (int f = 0; f < 64; ++f) {
      const float4 qv0 = *(const float4*)&qsT[f][r0];
      const float4 qv1 = *(const float4*)&qsT[f][r0 + 4];
      const float4 rv0 = *(const float4*)&rs[f][c0];
      const float4 rv1 = *(const float4*)&rs[f][c0 + 4];
      const float qr[8] = {qv0.x, qv0.y, qv0.z, qv0.w, qv1.x, qv1.y, qv1.z, qv1.w};
      const float rc[8] = {rv0.x, rv0.y, rv0.z, rv0.w, rv1.x, rv1.y, rv1.z, rv1.w};
#pragma unroll
      for (int r = 0; r < 8; ++r)
#pragma unroll
        for (int c = 0; c < 8; ++c) acc[r][c] += qr[r] * rc[c];
    }

    // per-row argmax over [rot, -rot]; reduce over the 8 col-lanes of this h.
    // Tie rule: greater value, then lower index (pos indices < neg indices).
    const int h = hp * 2 + hloc;
    unsigned long long packed = 0ull;
#pragma unroll
    for (int r = 0; r < 8; ++r) {
      float bv = -3.4e38f;
      int bi = 0;
#pragma unroll
      for (int c = 0; c < 8; ++c) {
        const int i = i0 + c;
        const float vp = acc[r][c];
        if (vp > bv || (vp == bv && i < bi)) { bv = vp; bi = i; }
        const float vn = -vp;
        if (vn > bv || (vn == bv && (i + 64) < bi)) { bv = vn; bi = i + 64; }
      }
#pragma unroll
      for (int off = 1; off < 8; off <<= 1) {
        const float ov = __shfl_xor(bv, off);
        const int oi = __shfl_xor(bi, off);
        if (ov > bv || (ov == bv && oi < bi)) { bv = ov; bi = oi; }
      }
      packed |= ((unsigned long long)(unsigned int)(bi & 0xff)) << (8 * r);
    }
    if ((colg & 7) == 0)
      *(unsigned long long*)&bucket[((size_t)(b * HH + h)) * SS + (size_t)tile * 128 + r0] = packed;
  }
}

// ---------------------------------------------------------------------------
// Kernel 2: stable counting sort per (b,h), 1024 threads.
// ---------------------------------------------------------------------------
__global__ __launch_bounds__(1024) void sort_kernel(const unsigned char* __restrict__ bucket,
                                                    int* __restrict__ sticker) {
  __shared__ unsigned char lb[SS];
  __shared__ unsigned int hist[NB * NCHUNK];
  __shared__ unsigned int ssum[1024];
  const int tid = threadIdx.x;
  const int bh = blockIdx.x;

  if (tid < 512)
    ((uint4*)lb)[tid] = ((const uint4*)(bucket + (size_t)bh * SS))[tid];
#pragma unroll
  for (int k = 0; k < (NB * NCHUNK) / 1024; ++k) hist[tid + k * 1024] = 0u;
  __syncthreads();

#pragma unroll
  for (int rep = 0; rep < SS / 1024; ++rep) {
    const int t = rep * 1024 + tid;
    atomicAdd(&hist[(int)lb[t] * NCHUNK + (t >> 6)], 1u);
  }
  __syncthreads();

  unsigned int segsum = 0u;
  const int base = tid * 16;
#pragma unroll
  for (int e = 0; e < 16; ++e) segsum += hist[base + e];
  ssum[tid] = segsum;
  __syncthreads();
  for (int off = 1; off < 1024; off <<= 1) {
    const unsigned int vv = (tid >= off) ? ssum[tid - off] : 0u;
    __syncthreads();
    ssum[tid] += vv;
    __syncthreads();
  }
  unsigned int run = ssum[tid] - segsum;
#pragma unroll
  for (int e = 0; e < 16; ++e) {
    const unsigned int tv = hist[base + e];
    hist[base + e] = run;
    run += tv;
  }
  __syncthreads();

  const int wid = tid >> 6, lane = tid & 63;
#pragma unroll
  for (int rep = 0; rep < NCHUNK / 16; ++rep) {
    const int c = rep * 16 + wid;
    const int t = c * 64 + lane;
    const int bk = lb[t];
    unsigned long long mm = ~0ull;
#pragma unroll
    for (int bit = 0; bit < 7; ++bit) {
      const unsigned long long bal = __ballot((bk >> bit) & 1);
      mm &= ((bk >> bit) & 1) ? bal : ~bal;
    }
    const int rank = __popcll(mm & ((1ull << lane) - 1ull));
    const int pos = (int)hist[bk * NCHUNK + c] + rank;
    sticker[(size_t)bh * SS + pos] = t;
  }
}

// ---------------------------------------------------------------------------
// Kernel 3: fused attention from precomputed bf16 qhat/vb + f32 snorm.
// Grid (BB/2, NB, HH) per b-half — bl in x so XCD = (bl + 4*bin) & 7 keeps
// each b's 8 MB qhat+vb working set on 2 XCDs' L2. Writes normalized o_h
// (bf16, layout b,t,h,d) and lse_h (f32, layout b,t,h) by original t.
// ---------------------------------------------------------------------------
__global__ __launch_bounds__(256) void attn_kernel(const unsigned short* __restrict__ qhat,
                                                   const unsigned short* __restrict__ vb,
                                                   const float* __restrict__ snorm,
                                                   const int* __restrict__ sticker,
                                                   unsigned short* __restrict__ so,
                                                   float* __restrict__ slogits,
                                                   const int b_base) {
  __shared__ __align__(16) unsigned short kbps[128 * 72];   // aliased: kb -> ps -> ob
  __shared__ __align__(16) unsigned short vt[64][136];
  __shared__ int st[128];
  __shared__ float sn_s[64];
  const int tid = threadIdx.x;
  const int bin = blockIdx.y, bl = blockIdx.x, h = blockIdx.z;
  const int b = b_base + bl;
  const int bh = b * HH + h;
  const int prev = (h * NB + bin + CHUNKS - 1) & (CHUNKS - 1);
  const int ph = prev >> 7, pbin = prev & 127;

  if (tid < 128) {
    const int j = tid;
    const int src = (j < 64) ? (bh * SS + bin * 64 + j)
                             : ((b * HH + ph) * SS + pbin * 64 + (j - 64));
    st[j] = sticker[src];
  }
  __syncthreads();

  {
    const int row = tid >> 1, half = tid & 1;
    const int trow = st[row];
    {
      const uint4* qsrc = (const uint4*)(qhat + ((size_t)b * SS + trow) * DD) + half * 4;
      uint4 q0 = qsrc[0], q1 = qsrc[1], q2 = qsrc[2], q3 = qsrc[3];
      unsigned short* kd = &kbps[row * 72 + half * 32];
      *(uint4*)&kd[0] = q0;
      *(uint4*)&kd[8] = q1;
      *(uint4*)&kd[16] = q2;
      *(uint4*)&kd[24] = q3;
    }
    {
      const uint4* vsrc = (const uint4*)(vb + ((size_t)b * SS + trow) * DD) + half * 4;
      uint4 w0 = vsrc[0], w1 = vsrc[1], w2 = vsrc[2], w3 = vsrc[3];
      unsigned int uu[16] = {w0.x, w0.y, w0.z, w0.w, w1.x, w1.y, w1.z, w1.w,
                             w2.x, w2.y, w2.z, w2.w, w3.x, w3.y, w3.z, w3.w};
#pragma unroll
      for (int m = 0; m < 16; ++m) {
        vt[half * 32 + 2 * m][row] = (unsigned short)(uu[m] & 0xffffu);
        vt[half * 32 + 2 * m + 1][row] = (unsigned short)(uu[m] >> 16);
      }
    }
  }
  if (tid < 64) sn_s[tid] = snorm[(size_t)b * SS + st[tid]];
  __syncthreads();

  const int lane = tid & 63, w = tid >> 6;
  const int r16 = lane & 15, g = lane >> 4;

  f32x4 acc[8];
#pragma unroll
  for (int n = 0; n < 8; ++n) acc[n] = (f32x4){0.f, 0.f, 0.f, 0.f};
  bf16x8 af0 = *(const bf16x8*)&kbps[(16 * w + r16) * 72 + g * 8];
  bf16x8 af1 = *(const bf16x8*)&kbps[(16 * w + r16) * 72 + 32 + g * 8];
#pragma unroll
  for (int n = 0; n < 8; ++n) {
    bf16x8 bf0 = *(const bf16x8*)&kbps[(16 * n + r16) * 72 + g * 8];
    bf16x8 bf1 = *(const bf16x8*)&kbps[(16 * n + r16) * 72 + 32 + g * 8];
    acc[n] = __builtin_amdgcn_mfma_f32_16x16x32_bf16(af0, bf0, acc[n], 0, 0, 0);
    acc[n] = __builtin_amdgcn_mfma_f32_16x16x32_bf16(af1, bf1, acc[n], 0, 0, 0);
  }

  int tkj[8];
#pragma unroll
  for (int n = 0; n < 8; ++n) tkj[n] = st[16 * n + r16];

  float lse4[4];
#pragma unroll
  for (int i = 0; i < 4; ++i) {
    const int q = 16 * w + 4 * g + i;
    const int tq = st[q];
    const float sq = sn_s[q] * 0.125f;
    float mm = -3.4e38f;
#pragma unroll
    for (int n = 0; n < 8; ++n) {
      float s = acc[n][i] * sq;
      s = (tkj[n] > tq) ? -1e38f : ((tkj[n] == tq) ? -50000.f : s);
      acc[n][i] = s;
      mm = fmaxf(mm, s);
    }
    mm = fmaxf(mm, __shfl_xor(mm, 1));
    mm = fmaxf(mm, __shfl_xor(mm, 2));
    mm = fmaxf(mm, __shfl_xor(mm, 4));
    mm = fmaxf(mm, __shfl_xor(mm, 8));
    float sum = 0.f;
#pragma unroll
    for (int n = 0; n < 8; ++n) sum += __expf(acc[n][i] - mm);
    sum += __shfl_xor(sum, 1);
    sum += __shfl_xor(sum, 2);
    sum += __shfl_xor(sum, 4);
    sum += __shfl_xor(sum, 8);
    const float lse = mm + logf(sum);
    lse4[i] = lse;
#pragma unroll
    for (int n = 0; n < 8; ++n) acc[n][i] = __expf(acc[n][i] - lse);
  }

  __syncthreads();  // kb reads done -> overwrite with ps

#pragma unroll
  for (int i = 0; i < 4; ++i) {
    const int q = 16 * w + 4 * g + i;
#pragma unroll
    for (int n = 0; n < 8; ++n)
      kbps[q * 136 + 16 * n + r16] = f2b(acc[n][i]);
  }
  if (r16 == 0) {
#pragma unroll
    for (int i = 0; i < 4; ++i) {
      const int q = 16 * w + 4 * g + i;
      slogits[((size_t)b * SS + st[q]) * HH + h] = lse4[i];
    }
  }
  __syncthreads();

  f32x4 o[4];
#pragma unroll
  for (int n = 0; n < 4; ++n) o[n] = (f32x4){0.f, 0.f, 0.f, 0.f};
#pragma unroll
  for (int kk = 0; kk < 4; ++kk) {
    bf16x8 pa = *(const bf16x8*)&kbps[(16 * w + r16) * 136 + kk * 32 + g * 8];
#pragma unroll
    for (int n = 0; n < 4; ++n) {
      bf16x8 vbf = *(const bf16x8*)&vt[16 * n + r16][kk * 32 + g * 8];
      o[n] = __builtin_amdgcn_mfma_f32_16x16x32_bf16(pa, vbf, o[n], 0, 0, 0);
    }
  }

  __syncthreads();  // ps reads done -> overwrite with ob
#pragma unroll
  for (int i = 0; i < 4; ++i) {
    const int q = 16 * w + 4 * g + i;
#pragma unroll
    for (int n = 0; n < 4; ++n)
      kbps[q * 72 + 16 * n + r16] = f2b(o[n][i]);
  }
  __syncthreads();

  {
    const int row = tid >> 2, q4 = tid & 3;
    uint4 x0 = *(const uint4*)&kbps[row * 72 + q4 * 16];
    uint4 x1 = *(const uint4*)&kbps[row * 72 + q4 * 16 + 8];
    unsigned short* dst = so + (((size_t)bl * SS + st[row]) * HH + h) * DD + q4 * 16;
    *(uint4*)&dst[0] = x0;
    *(uint4*)&dst[8] = x1;
  }
}

// ---------------------------------------------------------------------------
// Kernel 4: combine — out[b,t] = sum_h exp(l_h - LSE) * o_h[b,t,h].
// so layout (local b, t, h, d): contiguous per token.
// ---------------------------------------------------------------------------
__global__ __launch_bounds__(256) void gather_out_kernel(const unsigned short* __restrict__ so,
                                                         const float* __restrict__ slogits,
                                                         float* __restrict__ out,
                                                         const int b_base) {
  const int idx = blockIdx.x * 256 + threadIdx.x;  // (local bt, seg)
  const int seg = idx & 7;
  const int btl = idx >> 3;  // local row in [0, 4*SS)

  const float* lrow = slogits + ((size_t)b_base * SS + btl) * HH;
  float4 l0 = ((const float4*)lrow)[0];
  float4 l1 = ((const float4*)lrow)[1];
  float l[8] = {l0.x, l0.y, l0.z, l0.w, l1.x, l1.y, l1.z, l1.w};
  float m = -3.4e38f;
#pragma unroll
  for (int h = 0; h < HH; ++h) m = fmaxf(m, l[h]);
  float sum = 0.f;
#pragma unroll
  for (int h = 0; h < HH; ++h) sum += __expf(l[h] - m);
  const float lse = m + logf(sum);

  float acc[8];
#pragma unroll
  for (int k = 0; k < 8; ++k) acc[k] = 0.f;
#pragma unroll
  for (int h = 0; h < HH; ++h) {
    const float wgt = __expf(l[h] - lse);
    uint4 u = *(const uint4*)(so + ((size_t)btl * HH + h) * DD + seg * 8);
    const unsigned int uu[4] = {u.x, u.y, u.z, u.w};
#pragma unroll
    for (int k = 0; k < 4; ++k) {
      acc[2 * k] += wgt * b2f((unsigned short)(uu[k] & 0xffffu));
      acc[2 * k + 1] += wgt * b2f((unsigned short)(uu[k] >> 16));
    }
  }
  float* dst = out + ((size_t)b_base * SS + btl) * DD + seg * 8;
  float4 o0, o1;
  o0.x = acc[0]; o0.y = acc[1]; o0.z = acc[2]; o0.w = acc[3];
  o1.x = acc[4]; o1.y = acc[5]; o1.z = acc[6]; o1.w = acc[7];
  ((float4*)dst)[0] = o0;
  ((float4*)dst)[1] = o1;
}

// ---------------------------------------------------------------------------
extern "C" void kernel_launch(void* const* d_in, const int* in_sizes, int n_in,
                              void* d_out, int out_size, void* d_ws, size_t ws_size,
                              hipStream_t stream) {
  (void)in_sizes; (void)n_in; (void)out_size; (void)ws_size;
  const float* qk = (const float*)d_in[0];
  const float* v = (const float*)d_in[1];
  const float* rot = (const float*)d_in[2];
  float* out = (float*)d_out;

  char* ws = (char*)d_ws;
  int* sticker = (int*)ws;                                          // @0,   2 MB
  float* slogits = (float*)(ws + ((size_t)2 << 20));                // @2,   2 MB (b,t,h)
  float* snorm = (float*)(ws + ((size_t)4 << 20));                  // @4,   256 KB
  unsigned char* bucket = (unsigned char*)(ws + ((size_t)4 << 20) + ((size_t)256 << 10));  // 512 KB
  unsigned short* qhat = (unsigned short*)(ws + ((size_t)5 << 20)); // @5,   8 MB
  unsigned short* vb = (unsigned short*)(ws + ((size_t)13 << 20));  // @13,  8 MB
  unsigned short* so = (unsigned short*)(ws + ((size_t)21 << 20));  // @21, 32 MB (half-batch)

  prep_kernel<<<(BB * SS * 8) / 256, 256, 0, stream>>>(qk, v, qhat, vb, snorm);
  hash_kernel<<<dim3(SS / 128, BB), 256, 0, stream>>>(qk, rot, bucket);
  sort_kernel<<<BB * HH, 1024, 0, stream>>>(bucket, sticker);

  for (int half = 0; half < 2; ++half) {
    const int b_base = half * (BB / 2);
    attn_kernel<<<dim3(BB / 2, NB, HH), 256, 0, stream>>>(qhat, vb, snorm, sticker, so, slogits, b_base);
    gather_out_kernel<<<(BB / 2 * SS * 8) / 256, 256, 0, stream>>>(so, slogits, out, b_base);
  }
}